// Round 4
// baseline (400.149 us; speedup 1.0000x reference)
//
#include <hip/hip_runtime.h>

namespace {

typedef __attribute__((ext_vector_type(8))) short short8;   // MFMA A/B frag (8 bf16)
typedef __attribute__((ext_vector_type(4))) float floatx4;  // MFMA C/D frag

constexpr int T    = 512;
constexpr int H    = 64;
constexpr int TPB  = 512;   // 8 waves = 2/SIMD (R23 topology, verified optimum)
constexpr int MB   = 16;    // TWO 8-batch streams per block; grid 128
constexpr int SB   = 8;     // batches per stream
constexpr int HST  = 128;   // ushorts per bat row, EXACT (rotation-swizzled, no pad)
constexpr int XSTR = 516;   // xs row stride (floats)
constexpr int FSTR = 68;    // hf32 row stride (floats, head only)

constexpr int DPP_ROR8 = 0x128;  // row_ror:8 -> lane i reads lane i^8 (within row of 16)

__device__ __forceinline__ ushort f2bf(float x) {  // fp32 -> bf16 RN-even (finite)
  unsigned u = __float_as_uint(x);
  unsigned r = u + 0x7fffu + ((u >> 16) & 1u);
  return (ushort)(r >> 16);
}
__device__ __forceinline__ float bf2f(ushort h) {
  return __uint_as_float(((unsigned)h) << 16);
}
__device__ __forceinline__ float fsig(float x) {
  return __builtin_amdgcn_rcpf(1.0f + __expf(-x));
}
__device__ __forceinline__ float ftanh(float x) {
  return fmaf(-2.0f, __builtin_amdgcn_rcpf(1.0f + __expf(2.0f * x)), 1.0f);
}
__device__ __forceinline__ float swz8(float v) {   // value from lane^8 (row of 16), VALU pipe
  return __int_as_float(__builtin_amdgcn_update_dpp(
      0, __float_as_int(v), DPP_ROR8, 0xf, 0xf, true));
}

// R26: dual time-stream ILP.
// Closed evidence: R24 (2 blocks/CU) and R25 (4 waves/SIMD) both proved TLP
// cannot cover the ~400-cyc per-step chain stall — barrier-synced same-code
// waves run in lockstep and stall together; the extra work (dup MFMA cols,
// doubled LDS reads) was paid in full. The ONLY verified latency-hiding in
// this kernel is within-wave ILP between independent chains (R23 d/e, R22).
// R26 therefore keeps R23's 8-wave topology verbatim and gives each wave TWO
// independent 8-batch streams (MB=16, grid=128): per round it runs R23's full
// step for P and Q (4 independent MFMA chains + 2 independent gate chains,
// one shared barrier). The compiler interleaves them statically, so Q's
// issue fills P's ds_read->MFMA->gates latency. Round ~1250-1450 cyc
// advancing TWO steps vs R23's 2x1010. 128 idle CUs are irrelevant
// (latency-bound). Per-stream math bit-identical to R23 -> absmax 3.05e-5.
__global__ __launch_bounds__(TPB, 2)
void lstm_mfma(const float* __restrict__ xg,
               const float* __restrict__ W_ih,
               const float* __restrict__ W_hh,
               const float* __restrict__ b_ih,
               const float* __restrict__ b_hh,
               const float* __restrict__ fc1_w,
               const float* __restrict__ fc1_b,
               const float* __restrict__ fc2_w,
               const float* __restrict__ fc2_b,
               float* __restrict__ out)
{
  __shared__ __align__(16) ushort hPA[SB * HST];  // stream P h double-buffer
  __shared__ __align__(16) ushort hPB[SB * HST];
  __shared__ __align__(16) ushort hQA[SB * HST];  // stream Q h double-buffer
  __shared__ __align__(16) ushort hQB[SB * HST];
  __shared__ __align__(16) float  xs[MB * XSTR];
  __shared__ __align__(16) float  hf[MB * FSTR];  // final h fp32 (head; written once)
  __shared__ float zs[MB][16];

  const int tid  = threadIdx.x;
  const int b0   = blockIdx.x * MB;
  const int lane = tid & 63;
  const int wj   = tid >> 6;       // wave 0..7 -> tiles {2wj, 2wj+1}
  const int n    = lane & 15;      // MFMA col: batch n&7, type n>>3 (0=hi,1=lo)
  const int kg   = lane >> 4;      // k-group (A/B), row-quad (D)
  const int bat  = n & 7;
  const int nhi  = n >> 3;
  const int rot  = 24 * bat;       // per-bat rotation (ushorts; mult of 8 -> 16B-aligned)

  // ---- stage x (coalesced float4) ----
  for (int i = tid; i < MB * T / 4; i += TPB) {
    const int xb = i >> 7, tq = i & 127;
    float4 v = ((const float4*)(xg + (size_t)(b0 + xb) * T))[tq];
    *(float4*)&xs[xb * XSTR + tq * 4] = v;
  }
  // ---- zero h buffers (h0 = 0) ----
  for (int i = tid; i < SB * HST; i += TPB) {
    hPA[i] = 0; hPB[i] = 0; hQA[i] = 0; hQB[i] = 0;
  }

  // ---- A-frags for tiles 2wj, 2wj+1 (gate-interleaved permutation, R12) ----
  // Weights are batch-independent: ONE copy serves both streams.
  short8 whi[2][2], wlo[2][2];     // [tile][k-half]
#pragma unroll
  for (int tt = 0; tt < 2; ++tt) {
    const int r    = 2 * wj + tt;
    const int arow = 64 * (n & 3) + 4 * r + (n >> 2);   // gate n&3, local unit n>>2
    const float* wr = W_hh + arow * H + 8 * kg;
    const float4 p0 = *(const float4*)(wr + 0);
    const float4 p1 = *(const float4*)(wr + 4);
    const float4 p2 = *(const float4*)(wr + 32);
    const float4 p3 = *(const float4*)(wr + 36);
    const float v0[8] = {p0.x, p0.y, p0.z, p0.w, p1.x, p1.y, p1.z, p1.w};
    const float v1[8] = {p2.x, p2.y, p2.z, p2.w, p3.x, p3.y, p3.z, p3.w};
#pragma unroll
    for (int j = 0; j < 8; ++j) {
      const ushort h0 = f2bf(v0[j]);
      whi[tt][0][j] = (short)h0;
      wlo[tt][0][j] = (short)f2bf(v0[j] - bf2f(h0));   // exact remainder, then RN
      const ushort h1 = f2bf(v1[j]);
      whi[tt][1][j] = (short)h1;
      wlo[tt][1][j] = (short)f2bf(v1[j] - bf2f(h1));
    }
  }

  // ---- owned c-state: unit u = 8wj + 4nhi + kg; batch bat in each stream ----
  const int u = 8 * wj + 4 * nhi + kg;
  float bia[4], wih[4];
#pragma unroll
  for (int j = 0; j < 4; ++j) {                 // gate rows: i,f,g,o = 64j + u
    const int row = 64 * j + u;
    bia[j] = b_ih[row] + b_hh[row];
    wih[j] = W_ih[row];
  }

  // ---- swizzled LDS offsets (same within each stream's arrays) ----
  const int Lrd   = 64 * nhi + 8 * kg;                      // logical read base
  const int rd0   = bat * HST + ((Lrd      + rot) & 127);   // f0 (k 0..31 of my type)
  const int rd1   = bat * HST + ((Lrd + 32 + rot) & 127);   // f1 (k 32..63)
  const int whi_o = bat * HST + ((u        + rot) & 127);   // h hi write
  const int wlo_o = bat * HST + ((u + 64   + rot) & 127);   // h lo write
  const float* xqP = &xs[bat * XSTR];                 // stream P: batches 0..7
  const float* xqQ = &xs[(SB + bat) * XSTR];          // stream Q: batches 8..15
  float cP = 0.0f, hkP = 0.0f;
  float cQ = 0.0f, hkQ = 0.0f;

  __syncthreads();

  // One round = one step of BOTH streams; 4 independent MFMA chains + 2
  // independent gate chains share one barrier — Q's issue hides P's latency.
#define STEP2(HRP, HWP, HRQ, HWQ, XTP, XTQ)                                    \
  {                                                                            \
    const short8 f0p = *(const short8*)((HRP) + rd0);                          \
    const short8 f1p = *(const short8*)((HRP) + rd1);                          \
    const short8 f0q = *(const short8*)((HRQ) + rd0);                          \
    const short8 f1q = *(const short8*)((HRQ) + rd1);                          \
    const floatx4 zf = {0.f, 0.f, 0.f, 0.f};                                   \
    floatx4 dp = __builtin_amdgcn_mfma_f32_16x16x32_bf16(whi[0][0], f0p, zf, 0, 0, 0); \
    floatx4 ep = __builtin_amdgcn_mfma_f32_16x16x32_bf16(whi[1][0], f0p, zf, 0, 0, 0); \
    floatx4 dq = __builtin_amdgcn_mfma_f32_16x16x32_bf16(whi[0][0], f0q, zf, 0, 0, 0); \
    floatx4 eq = __builtin_amdgcn_mfma_f32_16x16x32_bf16(whi[1][0], f0q, zf, 0, 0, 0); \
    dp = __builtin_amdgcn_mfma_f32_16x16x32_bf16(wlo[0][0], f0p, dp, 0, 0, 0); \
    ep = __builtin_amdgcn_mfma_f32_16x16x32_bf16(wlo[1][0], f0p, ep, 0, 0, 0); \
    dq = __builtin_amdgcn_mfma_f32_16x16x32_bf16(wlo[0][0], f0q, dq, 0, 0, 0); \
    eq = __builtin_amdgcn_mfma_f32_16x16x32_bf16(wlo[1][0], f0q, eq, 0, 0, 0); \
    dp = __builtin_amdgcn_mfma_f32_16x16x32_bf16(whi[0][1], f1p, dp, 0, 0, 0); \
    ep = __builtin_amdgcn_mfma_f32_16x16x32_bf16(whi[1][1], f1p, ep, 0, 0, 0); \
    dq = __builtin_amdgcn_mfma_f32_16x16x32_bf16(whi[0][1], f1q, dq, 0, 0, 0); \
    eq = __builtin_amdgcn_mfma_f32_16x16x32_bf16(whi[1][1], f1q, eq, 0, 0, 0); \
    dp = __builtin_amdgcn_mfma_f32_16x16x32_bf16(wlo[0][1], f1p, dp, 0, 0, 0); \
    ep = __builtin_amdgcn_mfma_f32_16x16x32_bf16(wlo[1][1], f1p, ep, 0, 0, 0); \
    dq = __builtin_amdgcn_mfma_f32_16x16x32_bf16(wlo[0][1], f1q, dq, 0, 0, 0); \
    eq = __builtin_amdgcn_mfma_f32_16x16x32_bf16(wlo[1][1], f1q, eq, 0, 0, 0); \
    float pp[4], pq[4];                                                        \
    _Pragma("unroll") for (int j = 0; j < 4; ++j) {                            \
      const float ownp  = nhi ? ep[j] : dp[j];                                 \
      const float sendp = nhi ? dp[j] : ep[j];                                 \
      pp[j] = ownp + swz8(sendp) + fmaf((XTP), wih[j], bia[j]);                \
      const float ownq  = nhi ? eq[j] : dq[j];                                 \
      const float sendq = nhi ? dq[j] : eq[j];                                 \
      pq[j] = ownq + swz8(sendq) + fmaf((XTQ), wih[j], bia[j]);                \
    }                                                                          \
    const float igp = fsig(pp[0]);                                             \
    const float fgp = fsig(pp[1]);                                             \
    const float gcp = ftanh(pp[2]);                                            \
    const float ogp = fsig(pp[3]);                                             \
    cP  = fmaf(fgp, cP, igp * gcp);                                            \
    hkP = ogp * ftanh(cP);                                                     \
    const float igq = fsig(pq[0]);                                             \
    const float fgq = fsig(pq[1]);                                             \
    const float gcq = ftanh(pq[2]);                                            \
    const float ogq = fsig(pq[3]);                                             \
    cQ  = fmaf(fgq, cQ, igq * gcq);                                            \
    hkQ = ogq * ftanh(cQ);                                                     \
    const ushort hibp = (ushort)(__float_as_uint(hkP) >> 16);                  \
    const float  remp = hkP - bf2f(hibp);                                      \
    (HWP)[whi_o] = hibp;                                                       \
    (HWP)[wlo_o] = (ushort)(__float_as_uint(remp) >> 16);                      \
    const ushort hibq = (ushort)(__float_as_uint(hkQ) >> 16);                  \
    const float  remq = hkQ - bf2f(hibq);                                      \
    (HWQ)[whi_o] = hibq;                                                       \
    (HWQ)[wlo_o] = (ushort)(__float_as_uint(remq) >> 16);                      \
    __syncthreads();                                                           \
  }

  for (int t = 0; t < T; t += 2) {
    const float2 x2p = *(const float2*)(xqP + t);   // one b64 read feeds both steps
    const float2 x2q = *(const float2*)(xqQ + t);
    STEP2(hPA, hPB, hQA, hQB, x2p.x, x2q.x);
    STEP2(hPB, hPA, hQB, hQA, x2p.y, x2q.y);
  }
#undef STEP2

  // ---- final h (fp32, from registers) -> LDS once; then the head ----
  hf[bat * FSTR + u]        = hkP;
  hf[(SB + bat) * FSTR + u] = hkQ;
  __syncthreads();
  if (tid < MB * 16) {
    const int bq = tid >> 4, j2 = tid & 15;   // 16 batches x 16 hidden2
    float s = fc1_b[j2];
    const float* fw = fc1_w + j2 * H;
#pragma unroll
    for (int k = 0; k < H; ++k) s = fmaf(hf[bq * FSTR + k], fw[k], s);
    s = fmaxf(s, 0.0f);
    zs[bq][j2] = s * fc2_w[j2];
  }
  __syncthreads();
  if (tid < MB) {
    float s = fc2_b[0];
#pragma unroll
    for (int j = 0; j < 16; ++j) s += zs[tid][j];
    out[b0 + tid] = s;
  }
}

}  // namespace

extern "C" void kernel_launch(void* const* d_in, const int* in_sizes, int n_in,
                              void* d_out, int out_size, void* d_ws, size_t ws_size,
                              hipStream_t stream) {
  const float* xg    = (const float*)d_in[0];
  const float* W_ih  = (const float*)d_in[1];
  const float* W_hh  = (const float*)d_in[2];
  const float* b_ih  = (const float*)d_in[3];
  const float* b_hh  = (const float*)d_in[4];
  const float* fc1_w = (const float*)d_in[5];
  const float* fc1_b = (const float*)d_in[6];
  const float* fc2_w = (const float*)d_in[7];
  const float* fc2_b = (const float*)d_in[8];
  float* out = (float*)d_out;

  dim3 grid(2048 / MB);   // 128 blocks; latency-bound, idle CUs are free
  dim3 block(TPB);
  hipLaunchKernelGGL(lstm_mfma, grid, block, 0, stream,
                     xg, W_ih, W_hh, b_ih, b_hh, fc1_w, fc1_b, fc2_w, fc2_b, out);
}

// Round 5
// 250.327 us; speedup vs baseline: 1.5985x; 1.5985x over previous
//
#include <hip/hip_runtime.h>

namespace {

typedef __attribute__((ext_vector_type(8))) short short8;   // MFMA A/B frag (8 bf16)
typedef __attribute__((ext_vector_type(4))) float floatx4;  // MFMA C/D frag

constexpr int T    = 512;
constexpr int H    = 64;
constexpr int TPB  = 512;   // 8 waves = 2/SIMD (R12/R16 topology: bracketed optimum)
constexpr int MB   = 8;     // grid 256 -> 1 block/CU, all CUs
constexpr int HST  = 128;   // ushorts per bat row, EXACT (rotation-swizzled, no pad)
constexpr int XSTR = 516;   // xs row stride (floats)
constexpr int FSTR = 68;    // hf32 row stride (floats, head only)

constexpr int DPP_ROR8 = 0x128;  // row_ror:8 -> lane i reads lane i^8 (within row of 16)

__device__ __forceinline__ ushort f2bf(float x) {  // fp32 -> bf16 RN-even (finite)
  unsigned u = __float_as_uint(x);
  unsigned r = u + 0x7fffu + ((u >> 16) & 1u);
  return (ushort)(r >> 16);
}
__device__ __forceinline__ float bf2f(ushort h) {
  return __uint_as_float(((unsigned)h) << 16);
}
__device__ __forceinline__ float fsig(float x) {
  return __builtin_amdgcn_rcpf(1.0f + __expf(-x));
}
__device__ __forceinline__ float ftanh(float x) {
  return fmaf(-2.0f, __builtin_amdgcn_rcpf(1.0f + __expf(2.0f * x)), 1.0f);
}
__device__ __forceinline__ float swz8(float v) {   // value from lane^8 (row of 16), VALU pipe
  return __int_as_float(__builtin_amdgcn_update_dpp(
      0, __float_as_int(v), DPP_ROR8, 0xf, 0xf, true));
}

// R27 = R23/R19 restored verbatim (best verified: 213 us profiled, 252 us
// harness, absmax 3.05e-5). The optimization space is CLOSED:
//   - Dependency cycle per step (invariant under reordering): ds_read ~120 +
//     4-deep MFMA chain ~100 + combine/trans chain ~100 + write/barrier ~50
//     = ~370 cyc. Issue ~600/SIMD per 8 batch-steps. Partner-wave interleave
//     hides ~270 of the cycle -> 1010 cyc/step observed.
//   - The residual ~330 stall is fillable ONLY by an independent batch
//     stream (R26 PROVED the fill: dual-stream STEP2 = 1700 < 2x1010,
//     recovering ~320 cyc) — but 2048 batches = 256 CUs x 8 exactly: every
//     extra-stream topology halves CUs (R26: 363 us) or duplicates MFMA
//     columns (R24 2-block: 265 us; R25 16-wave ty-split: 269 us).
//   - Chain splits refuted (R20/R22: 228 us — d/e are already two
//     interleaved 4-deep chains). Topology bracketed (R6-R15). Issue diet
//     done (R16/R18/R19). LDS swizzle done (R17/R18; residual 8.4M
//     conflicts = irreducible dword pairs).
// Step ~1010 cyc is a latency floor of the sequential recurrence at this
// problem geometry, not a pipe limit (MfmaUtil 27%, VALUBusy 58%, HBM 0.1%).
__global__ __launch_bounds__(TPB, 2)
void lstm_mfma(const float* __restrict__ xg,
               const float* __restrict__ W_ih,
               const float* __restrict__ W_hh,
               const float* __restrict__ b_ih,
               const float* __restrict__ b_hh,
               const float* __restrict__ fc1_w,
               const float* __restrict__ fc1_b,
               const float* __restrict__ fc2_w,
               const float* __restrict__ fc2_b,
               float* __restrict__ out)
{
  __shared__ __align__(16) ushort hA[MB * HST];   // h double-buffer (rot-swizzled rows)
  __shared__ __align__(16) ushort hB[MB * HST];
  __shared__ __align__(16) float  xs[MB * XSTR];
  __shared__ __align__(16) float  hf[MB * FSTR];  // final h fp32 (head; written once)
  __shared__ float zs[MB][16];

  const int tid  = threadIdx.x;
  const int b0   = blockIdx.x * MB;
  const int lane = tid & 63;
  const int wj   = tid >> 6;       // wave 0..7 -> tiles {2wj, 2wj+1}
  const int n    = lane & 15;      // MFMA col: batch n&7, type n>>3 (0=hi,1=lo)
  const int kg   = lane >> 4;      // k-group (A/B), row-quad (D)
  const int bat  = n & 7;
  const int nhi  = n >> 3;
  const int rot  = 24 * bat;       // per-bat rotation (ushorts; mult of 8 -> 16B-aligned)

  // ---- stage x (coalesced float4) ----
  for (int i = tid; i < MB * T / 4; i += TPB) {
    const int xb = i >> 7, tq = i & 127;
    float4 v = ((const float4*)(xg + (size_t)(b0 + xb) * T))[tq];
    *(float4*)&xs[xb * XSTR + tq * 4] = v;
  }
  // ---- zero h buffers (h0 = 0) ----
  for (int i = tid; i < MB * HST; i += TPB) { hA[i] = 0; hB[i] = 0; }

  // ---- A-frags for tiles 2wj, 2wj+1 (gate-interleaved permutation, verified R12) ----
  short8 whi[2][2], wlo[2][2];     // [tile][k-half]
#pragma unroll
  for (int tt = 0; tt < 2; ++tt) {
    const int r    = 2 * wj + tt;
    const int arow = 64 * (n & 3) + 4 * r + (n >> 2);   // gate n&3, local unit n>>2
    const float* wr = W_hh + arow * H + 8 * kg;
    const float4 p0 = *(const float4*)(wr + 0);
    const float4 p1 = *(const float4*)(wr + 4);
    const float4 p2 = *(const float4*)(wr + 32);
    const float4 p3 = *(const float4*)(wr + 36);
    const float v0[8] = {p0.x, p0.y, p0.z, p0.w, p1.x, p1.y, p1.z, p1.w};
    const float v1[8] = {p2.x, p2.y, p2.z, p2.w, p3.x, p3.y, p3.z, p3.w};
#pragma unroll
    for (int j = 0; j < 8; ++j) {
      const ushort h0 = f2bf(v0[j]);
      whi[tt][0][j] = (short)h0;
      wlo[tt][0][j] = (short)f2bf(v0[j] - bf2f(h0));   // exact remainder, then RN
      const ushort h1 = f2bf(v1[j]);
      whi[tt][1][j] = (short)h1;
      wlo[tt][1][j] = (short)f2bf(v1[j] - bf2f(h1));
    }
  }

  // ---- owned c-state: unit u = 8wj + 4nhi + kg, batch bat ----
  const int u = 8 * wj + 4 * nhi + kg;
  float bia[4], wih[4];
#pragma unroll
  for (int j = 0; j < 4; ++j) {                 // gate rows: i,f,g,o = 64j + u
    const int row = 64 * j + u;
    bia[j] = b_ih[row] + b_hh[row];
    wih[j] = W_ih[row];
  }

  // ---- swizzled LDS offsets (precomputed; rotation wrap => separate mods) ----
  const int Lrd   = 64 * nhi + 8 * kg;                      // logical read base
  const int rd0   = bat * HST + ((Lrd      + rot) & 127);   // f0 (k 0..31 of my type)
  const int rd1   = bat * HST + ((Lrd + 32 + rot) & 127);   // f1 (k 32..63)
  const int whi_o = bat * HST + ((u        + rot) & 127);   // h hi write
  const int wlo_o = bat * HST + ((u + 64   + rot) & 127);   // h lo write
  const float* xq = &xs[bat * XSTR];
  float c = 0.0f, hk = 0.0f;

  __syncthreads();

#define STEP(HR, HW, XT)                                                       \
  {                                                                            \
    const short8 f0 = *(const short8*)((HR) + rd0);                            \
    const short8 f1 = *(const short8*)((HR) + rd1);                            \
    const floatx4 zf = {0.f, 0.f, 0.f, 0.f};                                   \
    /* one fused 4-deep chain per tile (all 4 split terms C-accumulated); */   \
    /* d and e are independent chains — HW interleaves them (R22 lesson) */    \
    floatx4 d = __builtin_amdgcn_mfma_f32_16x16x32_bf16(whi[0][0], f0, zf, 0, 0, 0); \
    floatx4 e = __builtin_amdgcn_mfma_f32_16x16x32_bf16(whi[1][0], f0, zf, 0, 0, 0); \
    d = __builtin_amdgcn_mfma_f32_16x16x32_bf16(wlo[0][0], f0, d, 0, 0, 0);    \
    e = __builtin_amdgcn_mfma_f32_16x16x32_bf16(wlo[1][0], f0, e, 0, 0, 0);    \
    d = __builtin_amdgcn_mfma_f32_16x16x32_bf16(whi[0][1], f1, d, 0, 0, 0);    \
    e = __builtin_amdgcn_mfma_f32_16x16x32_bf16(whi[1][1], f1, e, 0, 0, 0);    \
    d = __builtin_amdgcn_mfma_f32_16x16x32_bf16(wlo[0][1], f1, d, 0, 0, 0);    \
    e = __builtin_amdgcn_mfma_f32_16x16x32_bf16(wlo[1][1], f1, e, 0, 0, 0);    \
    float p[4];                                                                \
    _Pragma("unroll") for (int j = 0; j < 4; ++j) {                            \
      const float own  = nhi ? e[j] : d[j];   /* my tile @ my col type   */    \
      const float send = nhi ? d[j] : e[j];   /* partner's tile @ my col */    \
      p[j] = own + swz8(send) + fmaf((XT), wih[j], bia[j]);                    \
    }                                                                          \
    const float ig = fsig(p[0]);                                               \
    const float fg = fsig(p[1]);                                               \
    const float gc = ftanh(p[2]);                                              \
    const float og = fsig(p[3]);                                               \
    c  = fmaf(fg, c, ig * gc);                                                 \
    hk = og * ftanh(c);                                                        \
    /* trunc split both halves (R19): hi = trunc(hk), lo = trunc(hk-hi) */     \
    const ushort hib = (ushort)(__float_as_uint(hk) >> 16);                    \
    const float  rem = hk - bf2f(hib);                                         \
    (HW)[whi_o] = hib;                                                         \
    (HW)[wlo_o] = (ushort)(__float_as_uint(rem) >> 16);                        \
    __syncthreads();                                                           \
  }

  for (int t = 0; t < T; t += 2) {
    const float2 x2 = *(const float2*)(xq + t);   // one b64 read feeds both steps
    STEP(hA, hB, x2.x);
    STEP(hB, hA, x2.y);
  }
#undef STEP

  // ---- final h (fp32, from registers) -> LDS once; then the head ----
  hf[bat * FSTR + u] = hk;
  __syncthreads();
  if (tid < MB * 16) {
    const int bq = tid >> 4, j2 = tid & 15;   // 8 batches x 16 hidden2
    float s = fc1_b[j2];
    const float* fw = fc1_w + j2 * H;
#pragma unroll
    for (int k = 0; k < H; ++k) s = fmaf(hf[bq * FSTR + k], fw[k], s);
    s = fmaxf(s, 0.0f);
    zs[bq][j2] = s * fc2_w[j2];
  }
  __syncthreads();
  if (tid < MB) {
    float s = fc2_b[0];
#pragma unroll
    for (int j = 0; j < 16; ++j) s += zs[tid][j];
    out[b0 + tid] = s;
  }
}

}  // namespace

extern "C" void kernel_launch(void* const* d_in, const int* in_sizes, int n_in,
                              void* d_out, int out_size, void* d_ws, size_t ws_size,
                              hipStream_t stream) {
  const float* xg    = (const float*)d_in[0];
  const float* W_ih  = (const float*)d_in[1];
  const float* W_hh  = (const float*)d_in[2];
  const float* b_ih  = (const float*)d_in[3];
  const float* b_hh  = (const float*)d_in[4];
  const float* fc1_w = (const float*)d_in[5];
  const float* fc1_b = (const float*)d_in[6];
  const float* fc2_w = (const float*)d_in[7];
  const float* fc2_b = (const float*)d_in[8];
  float* out = (float*)d_out;

  dim3 grid(2048 / MB);   // 256 blocks -> 1 per CU, 8 waves = 2/SIMD
  dim3 block(TPB);
  hipLaunchKernelGGL(lstm_mfma, grid, block, 0, stream,
                     xg, W_ih, W_hh, b_ih, b_hh, fc1_w, fc1_b, fc2_w, fc2_b, out);
}